// Round 1
// baseline (122.298 us; speedup 1.0000x reference)
//
#include <hip/hip_runtime.h>
#include <hip/hip_bf16.h>

// Problem constants: B=4, Q=256, K=256, H=512
#define B_ 4
#define Q_ 256
#define K_ 256
#define H_ 512
#define NEG (-1e9f)
#define TQ 4  // q-rows per fused block

// ---------------------------------------------------------------------------
// Kernel 1: fp32 projection GEMM.  out[r,c] = sum_h X[r,h] * W[h,c]
// rows = B*Q = 1024 (same for key), H = 512.  64x64 tile, K-step 16.
// grid = (rows/64, H/64, 2); z=0 -> query@Wq, z=1 -> key@Wk
// ---------------------------------------------------------------------------
__global__ __launch_bounds__(256) void proj_kernel(
    const float* __restrict__ Xq, const float* __restrict__ Xk,
    const float* __restrict__ Wq, const float* __restrict__ Wk,
    float* __restrict__ outq, float* __restrict__ outk)
{
    const float* X   = blockIdx.z ? Xk  : Xq;
    const float* W   = blockIdx.z ? Wk  : Wq;
    float*       out = blockIdx.z ? outk : outq;

    __shared__ float As[16][64 + 1];  // [k][row]
    __shared__ float Bs[16][64 + 1];  // [k][col]

    const int row0 = blockIdx.x * 64;
    const int col0 = blockIdx.y * 64;
    const int t  = threadIdx.x;
    const int tc = t % 16;   // col group
    const int tr = t / 16;   // row group

    float acc[4][4] = {};

    for (int kk = 0; kk < H_; kk += 16) {
        // load A tile (64 rows x 16 k), store transposed As[k][row]
        {
            const int k = t % 16, r = t / 16;
            #pragma unroll
            for (int p = 0; p < 4; ++p)
                As[k][r + p * 16] = X[(row0 + r + p * 16) * H_ + kk + k];
            // load B tile (16 k x 64 cols)
            const int c = t % 64, k2 = t / 64;
            #pragma unroll
            for (int p = 0; p < 4; ++p)
                Bs[k2 + p * 4][c] = W[(kk + k2 + p * 4) * H_ + col0 + c];
        }
        __syncthreads();
        #pragma unroll
        for (int k = 0; k < 16; ++k) {
            float a[4], b[4];
            #pragma unroll
            for (int i = 0; i < 4; ++i) a[i] = As[k][tr * 4 + i];
            #pragma unroll
            for (int j = 0; j < 4; ++j) b[j] = Bs[k][tc * 4 + j];
            #pragma unroll
            for (int i = 0; i < 4; ++i)
                #pragma unroll
                for (int j = 0; j < 4; ++j)
                    acc[i][j] += a[i] * b[j];
        }
        __syncthreads();
    }

    #pragma unroll
    for (int i = 0; i < 4; ++i)
        #pragma unroll
        for (int j = 0; j < 4; ++j)
            out[(row0 + tr * 4 + i) * H_ + col0 + tc * 4 + j] = acc[i][j];
}

// ---------------------------------------------------------------------------
// Kernel 2: fused scores -> masked softmax -> context.
// grid = (B, Q/TQ), block = 256 (4 waves).
// Each block: one batch b, TQ=4 consecutive q rows.
//   score phase : wave w owns k in [w*64, w*64+64); lanes own h-chunk of 8.
//   softmax     : wave w owns q-row w.
//   context     : wave w owns k in [w*64, ...); partials combined via LDS.
// ---------------------------------------------------------------------------
__device__ __forceinline__ void load8(const float* __restrict__ p, float* r) {
    const float4* p4 = (const float4*)p;
    float4 a = p4[0], b = p4[1];
    r[0] = a.x; r[1] = a.y; r[2] = a.z; r[3] = a.w;
    r[4] = b.x; r[5] = b.y; r[6] = b.z; r[7] = b.w;
}

__global__ __launch_bounds__(256) void fused_attn(
    const float* __restrict__ qp, const float* __restrict__ kp,
    const float* __restrict__ value, const int* __restrict__ vlen,
    const float* __restrict__ wv, float* __restrict__ out)
{
    const int b    = blockIdx.x;
    const int q0   = blockIdx.y * TQ;
    const int t    = threadIdx.x;
    const int wave = t >> 6;
    const int lane = t & 63;
    const int h0   = lane * 8;          // this lane's h-chunk

    __shared__ float sc[TQ][K_];        // scores, then attention weights (4 KB)
    __shared__ float ctxp[4][TQ][H_];   // per-wave context partials (32 KB)

    // --- load per-lane q fragments and wv fragment into registers ---
    float qreg[TQ][8];
    float wvr[8];
    #pragma unroll
    for (int qi = 0; qi < TQ; ++qi)
        load8(&qp[(b * Q_ + q0 + qi) * H_ + h0], qreg[qi]);
    load8(&wv[h0], wvr);

    const int kb = wave * 64;

    // ---------------- score phase ----------------
    for (int k = 0; k < 64; ++k) {
        const int kk = kb + k;
        float kr[8];
        load8(&kp[(b * K_ + kk) * H_ + h0], kr);

        float acc[TQ] = {0.f, 0.f, 0.f, 0.f};
        #pragma unroll
        for (int j = 0; j < 8; ++j) {
            const float kv = kr[j];
            const float w  = wvr[j];
            #pragma unroll
            for (int qi = 0; qi < TQ; ++qi) {
                float x  = qreg[qi][j] + kv;
                float e  = __expf(x + x);                       // e^(2x)
                float r  = __builtin_amdgcn_rcpf(e + 1.0f);
                float th = __builtin_fmaf(-2.0f, r, 1.0f);      // tanh(x)
                acc[qi] += th * w;
            }
        }
        // butterfly reduce each acc over 64 lanes
        #pragma unroll
        for (int s = 32; s > 0; s >>= 1) {
            #pragma unroll
            for (int qi = 0; qi < TQ; ++qi)
                acc[qi] += __shfl_xor(acc[qi], s);
        }
        if (lane == 0) {
            #pragma unroll
            for (int qi = 0; qi < TQ; ++qi) sc[qi][kk] = acc[qi];
        }
    }
    __syncthreads();

    // ---------------- masked softmax (wave w -> row w) ----------------
    {
        const int q     = wave;
        const int valid = vlen[b];
        float sv[4];
        float mx = -1e30f;
        #pragma unroll
        for (int j = 0; j < 4; ++j) {
            const int k = lane + 64 * j;
            float s = sc[q][k];
            if (k >= valid) s = NEG;
            sv[j] = s;
            mx = fmaxf(mx, s);
        }
        #pragma unroll
        for (int d = 32; d > 0; d >>= 1) mx = fmaxf(mx, __shfl_xor(mx, d));
        float ev[4], sum = 0.f;
        #pragma unroll
        for (int j = 0; j < 4; ++j) {
            ev[j] = __expf(sv[j] - mx);
            sum  += ev[j];
        }
        #pragma unroll
        for (int d = 32; d > 0; d >>= 1) sum += __shfl_xor(sum, d);
        #pragma unroll
        for (int j = 0; j < 4; ++j)
            sc[q][lane + 64 * j] = ev[j] / sum;
    }
    __syncthreads();

    // ---------------- context phase (wave w -> k range, all q) ----------------
    float ctx[TQ][8] = {};
    for (int k = 0; k < 64; ++k) {
        const int kk = kb + k;
        float vr[8];
        load8(&value[(b * K_ + kk) * H_ + h0], vr);
        float a0 = sc[0][kk], a1 = sc[1][kk], a2 = sc[2][kk], a3 = sc[3][kk];
        #pragma unroll
        for (int j = 0; j < 8; ++j) {
            ctx[0][j] += a0 * vr[j];
            ctx[1][j] += a1 * vr[j];
            ctx[2][j] += a2 * vr[j];
            ctx[3][j] += a3 * vr[j];
        }
    }
    #pragma unroll
    for (int qi = 0; qi < TQ; ++qi) {
        float4* d = (float4*)&ctxp[wave][qi][h0];
        d[0] = make_float4(ctx[qi][0], ctx[qi][1], ctx[qi][2], ctx[qi][3]);
        d[1] = make_float4(ctx[qi][4], ctx[qi][5], ctx[qi][6], ctx[qi][7]);
    }
    __syncthreads();

    // finalize: wave w sums partials for q-row w and writes out
    {
        const int q = wave;
        float o[8];
        #pragma unroll
        for (int j = 0; j < 8; ++j)
            o[j] = ctxp[0][q][h0 + j] + ctxp[1][q][h0 + j] +
                   ctxp[2][q][h0 + j] + ctxp[3][q][h0 + j];
        float4* d = (float4*)&out[(b * Q_ + q0 + q) * H_ + h0];
        d[0] = make_float4(o[0], o[1], o[2], o[3]);
        d[1] = make_float4(o[4], o[5], o[6], o[7]);
    }
}

// ---------------------------------------------------------------------------
extern "C" void kernel_launch(void* const* d_in, const int* in_sizes, int n_in,
                              void* d_out, int out_size, void* d_ws, size_t ws_size,
                              hipStream_t stream)
{
    const float* query = (const float*)d_in[0];
    const float* key   = (const float*)d_in[1];
    const float* value = (const float*)d_in[2];
    const int*   vlen  = (const int*)  d_in[3];
    const float* Wq    = (const float*)d_in[4];
    const float* Wk    = (const float*)d_in[5];
    const float* wv    = (const float*)d_in[6];
    float*       outp  = (float*)d_out;

    float* qp = (float*)d_ws;              // [B*Q, H] = 2 MB
    float* kp = qp + (size_t)B_ * Q_ * H_; // [B*K, H] = 2 MB

    dim3 g1(B_ * Q_ / 64, H_ / 64, 2);     // (16, 8, 2)
    proj_kernel<<<g1, 256, 0, stream>>>(query, key, Wq, Wk, qp, kp);

    dim3 g2(B_, Q_ / TQ);                  // (4, 64)
    fused_attn<<<g2, 256, 0, stream>>>(qp, kp, value, vlen, wv, outp);
}

// Round 2
// 94.748 us; speedup vs baseline: 1.2908x; 1.2908x over previous
//
#include <hip/hip_runtime.h>
#include <hip/hip_bf16.h>

// Problem constants: B=4, Q=256, K=256, H=512
#define B_ 4
#define Q_ 256
#define K_ 256
#define H_ 512
#define NEG (-1e9f)
#define TQ 4  // q-rows per fused block
// pre-scale factor folded into projections: 2*log2(e), so exp2(q'+k') = e^{2(q+k)}
#define PRESCALE 2.885390081777927f

// ---------------------------------------------------------------------------
// Kernel 1: fp32 projection GEMM.  out[r,c] = SCALE * sum_h X[r,h] * W[h,c]
// 64x64 tile, K-step 16, float4 LDS staging (pad 68 keeps 16B alignment).
// grid = (16, 8, 2); z=0 -> query@Wq, z=1 -> key@Wk.
// z=1 tiles whose k-range is fully masked (k0 >= valid_len[b]) are skipped.
// ---------------------------------------------------------------------------
__global__ __launch_bounds__(256) void proj_kernel(
    const float* __restrict__ Xq, const float* __restrict__ Xk,
    const float* __restrict__ Wq, const float* __restrict__ Wk,
    float* __restrict__ outq, float* __restrict__ outk,
    const int* __restrict__ vlen)
{
    const int z    = blockIdx.z;
    const int row0 = blockIdx.x * 64;
    if (z) {  // kp rows >= valid_len[b] are never read downstream
        const int b = row0 >> 8, k0 = row0 & 255;
        if (k0 >= vlen[b]) return;
    }
    const float* X   = z ? Xk : Xq;
    const float* W   = z ? Wk : Wq;
    float*       out = z ? outk : outq;

    __shared__ float As[16][68];  // [k][row], row-start 272B = 16B aligned
    __shared__ float Bs[16][68];  // [k][col]

    const int col0 = blockIdx.y * 64;
    const int t  = threadIdx.x;
    const int tc = t & 15;   // col group (4 cols)
    const int tr = t >> 4;   // row group (4 rows)

    // staging indices: one float4 per thread per tile
    const int ar = t >> 2;         // A row 0..63
    const int ac = (t & 3) * 4;    // A k-offset {0,4,8,12}
    const int bk = t >> 4;         // B k-row 0..15
    const int bc = (t & 15) * 4;   // B col offset

    float acc[4][4] = {};

    for (int kk = 0; kk < H_; kk += 16) {
        const float4 av = *(const float4*)&X[(row0 + ar) * H_ + kk + ac];
        const float4 bv = *(const float4*)&W[(kk + bk) * H_ + col0 + bc];
        As[ac + 0][ar] = av.x;
        As[ac + 1][ar] = av.y;
        As[ac + 2][ar] = av.z;
        As[ac + 3][ar] = av.w;
        *(float4*)&Bs[bk][bc] = bv;
        __syncthreads();
        #pragma unroll
        for (int k = 0; k < 16; ++k) {
            const float4 a = *(const float4*)&As[k][tr * 4];
            const float4 b = *(const float4*)&Bs[k][tc * 4];
            const float aa[4] = {a.x, a.y, a.z, a.w};
            const float bb[4] = {b.x, b.y, b.z, b.w};
            #pragma unroll
            for (int i = 0; i < 4; ++i)
                #pragma unroll
                for (int j = 0; j < 4; ++j)
                    acc[i][j] = __builtin_fmaf(aa[i], bb[j], acc[i][j]);
        }
        __syncthreads();
    }

    #pragma unroll
    for (int i = 0; i < 4; ++i) {
        float4 o = make_float4(acc[i][0] * PRESCALE, acc[i][1] * PRESCALE,
                               acc[i][2] * PRESCALE, acc[i][3] * PRESCALE);
        *(float4*)&out[(row0 + tr * 4 + i) * H_ + col0 + tc * 4] = o;
    }
}

// ---------------------------------------------------------------------------
// Kernel 2: fused scores -> masked softmax -> context.
// grid = (B, Q/TQ) = (4, 64), block = 512 (8 waves).
//   score   : wave w owns k in [w*32, w*32+32) ∩ [0, valid); lane owns 8 h.
//             score = wsum + sum_h (-2 w_h) / (1 + e^{2(q_h+k_h)})
//             (projections pre-scaled by 2*log2e, so exp2(q'+k') = e^{2x})
//   softmax : wave w<4 owns q-row w; masked k -> NEG; valid==0 -> uniform.
//   context : wave w owns its k slice; 2-round LDS tree reduce (36 KB total).
// ---------------------------------------------------------------------------
__device__ __forceinline__ void load8(const float* __restrict__ p, float* r) {
    const float4* p4 = (const float4*)p;
    float4 a = p4[0], b = p4[1];
    r[0] = a.x; r[1] = a.y; r[2] = a.z; r[3] = a.w;
    r[4] = b.x; r[5] = b.y; r[6] = b.z; r[7] = b.w;
}

__global__ __launch_bounds__(512) void fused_attn(
    const float* __restrict__ qp, const float* __restrict__ kp,
    const float* __restrict__ value, const int* __restrict__ vlen,
    const float* __restrict__ wv, float* __restrict__ out)
{
    const int b    = blockIdx.x;
    const int q0   = blockIdx.y * TQ;
    const int t    = threadIdx.x;
    const int wave = t >> 6;        // 0..7
    const int lane = t & 63;
    const int h0   = lane * 8;

    __shared__ float sc[TQ][K_];        // scores -> attn weights (4 KB)
    __shared__ float ctxp[4][TQ][H_];   // context partials (32 KB)

    const int valid = vlen[b];

    // per-lane q fragments (pre-scaled) and wv fragment
    float qreg[TQ][8], w8[8];
    #pragma unroll
    for (int qi = 0; qi < TQ; ++qi)
        load8(&qp[(b * Q_ + q0 + qi) * H_ + h0], qreg[qi]);
    load8(&wv[h0], w8);

    float wsum = 0.f;
    #pragma unroll
    for (int j = 0; j < 8; ++j) wsum += w8[j];
    #pragma unroll
    for (int s = 32; s; s >>= 1) wsum += __shfl_xor(wsum, s);

    float wm[8];
    #pragma unroll
    for (int j = 0; j < 8; ++j) wm[j] = -2.f * w8[j];

    const int kb = wave * 32;

    // ---------------- score phase ----------------
    {
        const int kend = min(32, valid - kb);
        for (int k = 0; k < kend; ++k) {
            const int kk = kb + k;
            float kr[8];
            load8(&kp[(b * K_ + kk) * H_ + h0], kr);
            float acc[TQ] = {0.f, 0.f, 0.f, 0.f};
            #pragma unroll
            for (int j = 0; j < 8; ++j) {
                const float kv = kr[j], w = wm[j];
                #pragma unroll
                for (int qi = 0; qi < TQ; ++qi) {
                    const float e = exp2f(qreg[qi][j] + kv);       // e^{2x}
                    const float r = __builtin_amdgcn_rcpf(e + 1.f);
                    acc[qi] = __builtin_fmaf(w, r, acc[qi]);
                }
            }
            #pragma unroll
            for (int s = 32; s; s >>= 1) {
                #pragma unroll
                for (int qi = 0; qi < TQ; ++qi)
                    acc[qi] += __shfl_xor(acc[qi], s);
            }
            if (lane == 0) {
                #pragma unroll
                for (int qi = 0; qi < TQ; ++qi) sc[qi][kk] = wsum + acc[qi];
            }
        }
    }
    __syncthreads();

    // ---------------- masked softmax (waves 0..3) ----------------
    if (wave < TQ) {
        const int q = wave;
        if (valid == 0) {
            #pragma unroll
            for (int j = 0; j < 4; ++j) sc[q][lane + 64 * j] = 1.0f / K_;
        } else {
            float sv[4], mx = -3e38f;
            #pragma unroll
            for (int j = 0; j < 4; ++j) {
                const int k = lane + 64 * j;
                const float s = (k < valid) ? sc[q][k] : NEG;
                sv[j] = s;
                mx = fmaxf(mx, s);
            }
            #pragma unroll
            for (int d = 32; d; d >>= 1) mx = fmaxf(mx, __shfl_xor(mx, d));
            float ev[4], sum = 0.f;
            #pragma unroll
            for (int j = 0; j < 4; ++j) { ev[j] = __expf(sv[j] - mx); sum += ev[j]; }
            #pragma unroll
            for (int d = 32; d; d >>= 1) sum += __shfl_xor(sum, d);
            const float inv = 1.0f / sum;
            #pragma unroll
            for (int j = 0; j < 4; ++j) sc[q][lane + 64 * j] = ev[j] * inv;
        }
    }
    __syncthreads();

    // ---------------- context phase ----------------
    const int klim  = (valid == 0) ? K_ : valid;
    const int kend2 = min(32, klim - kb);
    float ctx[TQ][8] = {};
    for (int k = 0; k < kend2; ++k) {
        const int kk = kb + k;
        float vr[8];
        load8(&value[(b * K_ + kk) * H_ + h0], vr);
        const float a0 = sc[0][kk], a1 = sc[1][kk], a2 = sc[2][kk], a3 = sc[3][kk];
        #pragma unroll
        for (int j = 0; j < 8; ++j) {
            ctx[0][j] = __builtin_fmaf(a0, vr[j], ctx[0][j]);
            ctx[1][j] = __builtin_fmaf(a1, vr[j], ctx[1][j]);
            ctx[2][j] = __builtin_fmaf(a2, vr[j], ctx[2][j]);
            ctx[3][j] = __builtin_fmaf(a3, vr[j], ctx[3][j]);
        }
    }
    // round 1: waves 4..7 park their partials
    if (wave >= TQ) {
        #pragma unroll
        for (int qi = 0; qi < TQ; ++qi) {
            float4* d = (float4*)&ctxp[wave - 4][qi][h0];
            d[0] = make_float4(ctx[qi][0], ctx[qi][1], ctx[qi][2], ctx[qi][3]);
            d[1] = make_float4(ctx[qi][4], ctx[qi][5], ctx[qi][6], ctx[qi][7]);
        }
    }
    __syncthreads();
    // round 2: waves 0..3 fold partner partial in, park combined
    if (wave < TQ) {
        #pragma unroll
        for (int qi = 0; qi < TQ; ++qi) {
            #pragma unroll
            for (int j = 0; j < 8; ++j) ctx[qi][j] += ctxp[wave][qi][h0 + j];
        }
        __syncthreads();
        #pragma unroll
        for (int qi = 0; qi < TQ; ++qi) {
            float4* d = (float4*)&ctxp[wave][qi][h0];
            d[0] = make_float4(ctx[qi][0], ctx[qi][1], ctx[qi][2], ctx[qi][3]);
            d[1] = make_float4(ctx[qi][4], ctx[qi][5], ctx[qi][6], ctx[qi][7]);
        }
    } else {
        __syncthreads();
    }
    __syncthreads();
    // final: wave w<4 sums 4 partials for q-row w and writes out
    if (wave < TQ) {
        const int q = wave;
        float o[8];
        #pragma unroll
        for (int j = 0; j < 8; ++j)
            o[j] = (ctxp[0][q][h0 + j] + ctxp[1][q][h0 + j]) +
                   (ctxp[2][q][h0 + j] + ctxp[3][q][h0 + j]);
        float4* d = (float4*)&out[(b * Q_ + q0 + q) * H_ + h0];
        d[0] = make_float4(o[0], o[1], o[2], o[3]);
        d[1] = make_float4(o[4], o[5], o[6], o[7]);
    }
}

// ---------------------------------------------------------------------------
extern "C" void kernel_launch(void* const* d_in, const int* in_sizes, int n_in,
                              void* d_out, int out_size, void* d_ws, size_t ws_size,
                              hipStream_t stream)
{
    const float* query = (const float*)d_in[0];
    const float* key   = (const float*)d_in[1];
    const float* value = (const float*)d_in[2];
    const int*   vlen  = (const int*)  d_in[3];
    const float* Wq    = (const float*)d_in[4];
    const float* Wk    = (const float*)d_in[5];
    const float* wv    = (const float*)d_in[6];
    float*       outp  = (float*)d_out;

    float* qp = (float*)d_ws;              // [B*Q, H] = 2 MB (pre-scaled)
    float* kp = qp + (size_t)B_ * Q_ * H_; // [B*K, H] = 2 MB (pre-scaled)

    dim3 g1(B_ * Q_ / 64, H_ / 64, 2);     // (16, 8, 2)
    proj_kernel<<<g1, 256, 0, stream>>>(query, key, Wq, Wk, qp, kp, vlen);

    dim3 g2(B_, Q_ / TQ);                  // (4, 64)
    fused_attn<<<g2, 512, 0, stream>>>(qp, kp, value, vlen, wv, outp);
}

// Round 3
// 69.241 us; speedup vs baseline: 1.7663x; 1.3684x over previous
//
#include <hip/hip_runtime.h>
#include <hip/hip_bf16.h>

// Problem constants: B=4, Q=256, K=256, H=512
#define B_ 4
#define Q_ 256
#define K_ 256
#define H_ 512
#define NEG (-1e9f)
#define TQ 4  // q-rows per fused block
// pre-scale folded into projections: 2*log2(e), so exp2(q'+k') = e^{2(q+k)}
#define PRESCALE 2.885390081777927f

// ---------------------------------------------------------------------------
// Kernel 1: fp32 projection GEMM, q and k rows combined.
// rows 0..1023 = query@Wq, rows 1024..2047 = key@Wk.
// 64x64 tile, K-step 32, 512 threads (8 waves = 2/SIMD), acc[2][4]/thread.
// grid = (32, 8). Fully-masked key tiles (k0 >= valid_len[b]) are skipped.
// ---------------------------------------------------------------------------
__global__ __launch_bounds__(512) void proj_kernel(
    const float* __restrict__ Xq, const float* __restrict__ Xk,
    const float* __restrict__ Wq, const float* __restrict__ Wk,
    float* __restrict__ outq, float* __restrict__ outk,
    const int* __restrict__ vlen)
{
    const int rt   = blockIdx.x;          // 0..31
    const int z    = rt >> 4;             // 0 = q, 1 = k
    const int row0 = (rt & 15) * 64;
    if (z) {
        const int b = row0 >> 8, k0 = row0 & 255;
        if (k0 >= vlen[b]) return;        // masked kp rows never read downstream
    }
    const float* X   = z ? Xk : Xq;
    const float* W   = z ? Wk : Wq;
    float*       out = z ? outk : outq;

    __shared__ float As[32][68];  // [k][row] (transposed A tile)
    __shared__ float Bs[32][68];  // [k][col]

    const int col0 = blockIdx.y * 64;
    const int t  = threadIdx.x;
    const int tr = t >> 4;        // 0..31 -> rows 2tr, 2tr+1
    const int tc = t & 15;        // cols 4tc..4tc+3

    // staging indices (one float4 per thread per tile)
    const int arow = t >> 3;        // 0..63
    const int akc  = (t & 7) * 4;   // k offset 0..28
    const int bk   = t >> 4;        // 0..31
    const int bc   = (t & 15) * 4;

    float acc[2][4] = {};

    for (int kk = 0; kk < H_; kk += 32) {
        const float4 av = *(const float4*)&X[(row0 + arow) * H_ + kk + akc];
        const float4 bv = *(const float4*)&W[(kk + bk) * H_ + col0 + bc];
        __syncthreads();                       // prev-iter LDS reads done
        As[akc + 0][arow] = av.x;
        As[akc + 1][arow] = av.y;
        As[akc + 2][arow] = av.z;
        As[akc + 3][arow] = av.w;
        *(float4*)&Bs[bk][bc] = bv;
        __syncthreads();
        #pragma unroll
        for (int k = 0; k < 32; ++k) {
            const float2 a = *(const float2*)&As[k][2 * tr];
            const float4 b = *(const float4*)&Bs[k][4 * tc];
            const float aa[2] = {a.x, a.y};
            const float bb[4] = {b.x, b.y, b.z, b.w};
            #pragma unroll
            for (int i = 0; i < 2; ++i)
                #pragma unroll
                for (int j = 0; j < 4; ++j)
                    acc[i][j] = __builtin_fmaf(aa[i], bb[j], acc[i][j]);
        }
    }

    #pragma unroll
    for (int i = 0; i < 2; ++i) {
        float4 o = make_float4(acc[i][0] * PRESCALE, acc[i][1] * PRESCALE,
                               acc[i][2] * PRESCALE, acc[i][3] * PRESCALE);
        *(float4*)&out[(row0 + 2 * tr + i) * H_ + col0 + 4 * tc] = o;
    }
}

// ---------------------------------------------------------------------------
// Kernel 2: fused scores -> masked softmax -> context.
// grid = (B, Q/TQ) = (4, 64), 512 threads (8 waves).
// Score phase: thread t owns k = t&255 and q rows {t>>8, (t>>8)+2}.
//   Reduction over h is WITHIN-LANE (no cross-lane shuffles).
//   kp staged transposed in LDS, kp4[buf][h4][k][4], double-buffered (HC=16).
//   score(q,k) = sum_h -2*w_h * rcp(1 + e^{2(q_h+k_h)})   (wsum dropped:
//   softmax is shift-invariant, the constant cancels).
// Softmax: wave w<4 owns q-row w. Context: wave w owns k-slice [32w,32w+32).
// ---------------------------------------------------------------------------
__global__ __launch_bounds__(512) void fused_attn(
    const float* __restrict__ qp, const float* __restrict__ kp,
    const float* __restrict__ value, const int* __restrict__ vlen,
    const float* __restrict__ wv, float* __restrict__ out)
{
    const int b    = blockIdx.x;
    const int q0   = blockIdx.y * TQ;
    const int t    = threadIdx.x;
    const int wave = t >> 6;        // 0..7
    const int lane = t & 63;

    __shared__ float kp4[2][4][256][4];  // 32 KB, reused as ctxp later
    __shared__ float q_lds[TQ][H_];      // 8 KB
    __shared__ float wm_lds[H_];         // 2 KB  (-2 * wv)
    __shared__ float sc[TQ][K_];         // 4 KB

    const int valid = vlen[b];

    // ---- one-time staging: q rows (pre-scaled) and -2*wv ----
    {
        const int qi  = t >> 7;          // 0..3
        const int pos = (t & 127) * 4;
        *(float4*)&q_lds[qi][pos] = *(const float4*)&qp[(b * Q_ + q0 + qi) * H_ + pos];
        if (t < 128) {
            const float4 w = *(const float4*)&wv[t * 4];
            *(float4*)&wm_lds[t * 4] =
                make_float4(-2.f * w.x, -2.f * w.y, -2.f * w.z, -2.f * w.w);
        }
    }

    // ---- score phase: within-lane h-reduction ----
    const int k   = t & 255;
    const int qi0 = t >> 8;        // 0 or 1
    const int qi1 = qi0 + 2;
    const bool act = (k < valid);

    // staging mapping: 1024 float4 per 16-h chunk, 2 per thread
    int   skrow[2], sh4[2];
    const float* gsrc[2];
    #pragma unroll
    for (int r = 0; r < 2; ++r) {
        const int idx = t + r * 512;
        skrow[r] = idx & 255;
        sh4[r]   = idx >> 8;       // 0..3
        gsrc[r]  = &kp[(b * K_ + skrow[r]) * H_ + sh4[r] * 4];
    }

    // prologue: stage chunk 0 into buf 0
    #pragma unroll
    for (int r = 0; r < 2; ++r) {
        if (skrow[r] < valid) {
            const float4 v = *(const float4*)gsrc[r];
            *(float4*)&kp4[0][sh4[r]][skrow[r]][0] = v;
        }
    }
    __syncthreads();   // covers q_lds, wm_lds, kp4 buf0

    float s0 = 0.f, s1 = 0.f;

    for (int c = 0; c < 31; ++c) {
        const int buf = c & 1;
        const int hc  = c * 16;
        // issue next-chunk loads early (latency hides under compute)
        float4 nx0, nx1;
        if (skrow[0] < valid) nx0 = *(const float4*)(gsrc[0] + (hc + 16));
        if (skrow[1] < valid) nx1 = *(const float4*)(gsrc[1] + (hc + 16));
        // compute chunk c
        if (act) {
            #pragma unroll
            for (int h4 = 0; h4 < 4; ++h4) {
                const float4 kv = *(const float4*)&kp4[buf][h4][k][0];
                const float4 qa = *(const float4*)&q_lds[qi0][hc + h4 * 4];
                const float4 qb = *(const float4*)&q_lds[qi1][hc + h4 * 4];
                const float4 wm = *(const float4*)&wm_lds[hc + h4 * 4];
                const float kk4[4] = {kv.x, kv.y, kv.z, kv.w};
                const float qa4[4] = {qa.x, qa.y, qa.z, qa.w};
                const float qb4[4] = {qb.x, qb.y, qb.z, qb.w};
                const float wm4[4] = {wm.x, wm.y, wm.z, wm.w};
                #pragma unroll
                for (int j = 0; j < 4; ++j) {
                    const float e0 = __builtin_amdgcn_exp2f(qa4[j] + kk4[j]);
                    const float r0 = __builtin_amdgcn_rcpf(e0 + 1.f);
                    s0 = __builtin_fmaf(wm4[j], r0, s0);
                    const float e1 = __builtin_amdgcn_exp2f(qb4[j] + kk4[j]);
                    const float r1 = __builtin_amdgcn_rcpf(e1 + 1.f);
                    s1 = __builtin_fmaf(wm4[j], r1, s1);
                }
            }
        }
        // write next chunk into other buffer
        if (skrow[0] < valid) *(float4*)&kp4[buf ^ 1][sh4[0]][skrow[0]][0] = nx0;
        if (skrow[1] < valid) *(float4*)&kp4[buf ^ 1][sh4[1]][skrow[1]][0] = nx1;
        __syncthreads();
    }
    // final chunk (c = 31, buf 1)
    if (act) {
        const int hc = 31 * 16;
        #pragma unroll
        for (int h4 = 0; h4 < 4; ++h4) {
            const float4 kv = *(const float4*)&kp4[1][h4][k][0];
            const float4 qa = *(const float4*)&q_lds[qi0][hc + h4 * 4];
            const float4 qb = *(const float4*)&q_lds[qi1][hc + h4 * 4];
            const float4 wm = *(const float4*)&wm_lds[hc + h4 * 4];
            const float kk4[4] = {kv.x, kv.y, kv.z, kv.w};
            const float qa4[4] = {qa.x, qa.y, qa.z, qa.w};
            const float qb4[4] = {qb.x, qb.y, qb.z, qb.w};
            const float wm4[4] = {wm.x, wm.y, wm.z, wm.w};
            #pragma unroll
            for (int j = 0; j < 4; ++j) {
                const float e0 = __builtin_amdgcn_exp2f(qa4[j] + kk4[j]);
                const float r0 = __builtin_amdgcn_rcpf(e0 + 1.f);
                s0 = __builtin_fmaf(wm4[j], r0, s0);
                const float e1 = __builtin_amdgcn_exp2f(qb4[j] + kk4[j]);
                const float r1 = __builtin_amdgcn_rcpf(e1 + 1.f);
                s1 = __builtin_fmaf(wm4[j], r1, s1);
            }
        }
    }
    if (act) {
        sc[qi0][k] = s0;
        sc[qi1][k] = s1;
    }
    __syncthreads();

    // ---- masked softmax (waves 0..3, row = wave) ----
    if (wave < TQ) {
        const int q = wave;
        if (valid == 0) {
            #pragma unroll
            for (int j = 0; j < 4; ++j) sc[q][lane + 64 * j] = 1.0f / K_;
        } else {
            float sv[4], mx = -3e38f;
            #pragma unroll
            for (int j = 0; j < 4; ++j) {
                const int kk = lane + 64 * j;
                const float s = (kk < valid) ? sc[q][kk] : NEG;
                sv[j] = s;
                mx = fmaxf(mx, s);
            }
            #pragma unroll
            for (int d = 32; d; d >>= 1) mx = fmaxf(mx, __shfl_xor(mx, d));
            float ev[4], sum = 0.f;
            #pragma unroll
            for (int j = 0; j < 4; ++j) { ev[j] = __expf(sv[j] - mx); sum += ev[j]; }
            #pragma unroll
            for (int d = 32; d; d >>= 1) sum += __shfl_xor(sum, d);
            const float inv = 1.0f / sum;
            #pragma unroll
            for (int j = 0; j < 4; ++j) sc[q][lane + 64 * j] = ev[j] * inv;
        }
    }
    __syncthreads();

    // ---- context phase: wave w owns k in [32w, 32w+32) ----
    float* ctxp = (float*)kp4;   // [4][TQ][512] = 32 KB scratch (score done)
    const int h0   = lane * 8;
    const int kb   = wave * 32;
    const int klim = (valid == 0) ? K_ : valid;
    const int kend = min(32, klim - kb);

    float ctx[TQ][8] = {};
    for (int kc = 0; kc < kend; ++kc) {
        const int kk = kb + kc;
        const float4* vp = (const float4*)&value[(b * K_ + kk) * H_ + h0];
        const float4 v0 = vp[0], v1 = vp[1];
        const float vr[8] = {v0.x, v0.y, v0.z, v0.w, v1.x, v1.y, v1.z, v1.w};
        const float a0 = sc[0][kk], a1 = sc[1][kk], a2 = sc[2][kk], a3 = sc[3][kk];
        #pragma unroll
        for (int j = 0; j < 8; ++j) {
            ctx[0][j] = __builtin_fmaf(a0, vr[j], ctx[0][j]);
            ctx[1][j] = __builtin_fmaf(a1, vr[j], ctx[1][j]);
            ctx[2][j] = __builtin_fmaf(a2, vr[j], ctx[2][j]);
            ctx[3][j] = __builtin_fmaf(a3, vr[j], ctx[3][j]);
        }
    }
    // tree reduce across 8 waves via 32 KB scratch
    if (wave >= TQ) {
        #pragma unroll
        for (int qi = 0; qi < TQ; ++qi) {
            float* d = &ctxp[((wave - 4) * TQ + qi) * H_ + h0];
            ((float4*)d)[0] = make_float4(ctx[qi][0], ctx[qi][1], ctx[qi][2], ctx[qi][3]);
            ((float4*)d)[1] = make_float4(ctx[qi][4], ctx[qi][5], ctx[qi][6], ctx[qi][7]);
        }
    }
    __syncthreads();
    if (wave < TQ) {
        #pragma unroll
        for (int qi = 0; qi < TQ; ++qi) {
            float* d = &ctxp[(wave * TQ + qi) * H_ + h0];
            #pragma unroll
            for (int j = 0; j < 8; ++j) ctx[qi][j] += d[j];
            ((float4*)d)[0] = make_float4(ctx[qi][0], ctx[qi][1], ctx[qi][2], ctx[qi][3]);
            ((float4*)d)[1] = make_float4(ctx[qi][4], ctx[qi][5], ctx[qi][6], ctx[qi][7]);
        }
    }
    __syncthreads();
    if (wave < TQ) {
        const int q = wave;
        float o[8];
        #pragma unroll
        for (int j = 0; j < 8; ++j)
            o[j] = (ctxp[(0 * TQ + q) * H_ + h0 + j] + ctxp[(1 * TQ + q) * H_ + h0 + j]) +
                   (ctxp[(2 * TQ + q) * H_ + h0 + j] + ctxp[(3 * TQ + q) * H_ + h0 + j]);
        float4* d = (float4*)&out[(b * Q_ + q0 + q) * H_ + h0];
        d[0] = make_float4(o[0], o[1], o[2], o[3]);
        d[1] = make_float4(o[4], o[5], o[6], o[7]);
    }
}

// ---------------------------------------------------------------------------
extern "C" void kernel_launch(void* const* d_in, const int* in_sizes, int n_in,
                              void* d_out, int out_size, void* d_ws, size_t ws_size,
                              hipStream_t stream)
{
    const float* query = (const float*)d_in[0];
    const float* key   = (const float*)d_in[1];
    const float* value = (const float*)d_in[2];
    const int*   vlen  = (const int*)  d_in[3];
    const float* Wq    = (const float*)d_in[4];
    const float* Wk    = (const float*)d_in[5];
    const float* wv    = (const float*)d_in[6];
    float*       outp  = (float*)d_out;

    float* qp = (float*)d_ws;              // [B*Q, H] = 2 MB (pre-scaled)
    float* kp = qp + (size_t)B_ * Q_ * H_; // [B*K, H] = 2 MB (pre-scaled)

    dim3 g1(32, 8);                        // 256 blocks, 512 threads
    proj_kernel<<<g1, 512, 0, stream>>>(query, key, Wq, Wk, qp, kp, vlen);

    dim3 g2(B_, Q_ / TQ);                  // (4, 64)
    fused_attn<<<g2, 512, 0, stream>>>(qp, kp, value, vlen, wv, outp);
}